// Round 4
// baseline (134.382 us; speedup 1.0000x reference)
//
#include <hip/hip_runtime.h>
#include <math.h>

#define NR 6   // Fourier terms r=1..NR; trunc error ~I_{NR+1}(1)/I_0(1) ~ 1.3e-6

// J[r] = (r==0 ? 1 : 2) * I_r(t), modified Bessel, series (divisors fold to
// compile-time reciprocal multiplies after full unroll).
__device__ __forceinline__ void bessel_J(float t, float* J) {
    float h = 0.5f * t, q = h * h;
    float hp = 1.f, rf = 1.f;
#pragma unroll
    for (int r = 0; r <= NR; ++r) {
        if (r > 0) { hp *= h; rf *= (1.f / r); }
        float term = hp * rf, sum = term;
#pragma unroll
        for (int k = 1; k <= 12; ++k) {
            term *= q * (1.f / (k * (r + k)));
            sum += term;
        }
        J[r] = (r ? 2.f : 1.f) * sum;
    }
}

// ---------------------------------------------------------------------------
// Channel-attention collapsed map (exact): y4[2p+d] = A*y3[2p]+B*y3[2p+1]+C.
// ---------------------------------------------------------------------------
__device__ __forceinline__ void ca_coeffs(int p, int d,
        float s00, float s01, float s11, float m0, float m1,
        const float* __restrict__ wqkv, const float* __restrict__ bqkv,
        const float* __restrict__ t,    const float* __restrict__ wf,
        const float* __restrict__ bf,   float& A, float& B, float& C) {
    const float N = 1024.f;
    int c0 = 2 * p, c1 = 2 * p + 1;
    int c  = 2 * p + d;
    float Aa = 0.f, Bb = 0.f, Cc = 0.f;
#pragma unroll
    for (int e = 0; e < 2; ++e) {
        float wq0 = wqkv[c0 * 6 + e],     wq1 = wqkv[c1 * 6 + e];
        float bq0 = bqkv[c0 * 6 + e],     bq1 = bqkv[c1 * 6 + e];
        float wk0 = wqkv[c0 * 6 + 2 + e], wk1 = wqkv[c1 * 6 + 2 + e];
        float bk0 = bqkv[c0 * 6 + 2 + e], bk1 = bqkv[c1 * 6 + 2 + e];
        float wv0 = wqkv[c0 * 6 + 4 + e], wv1 = wqkv[c1 * 6 + 4 + e];
        float bv0 = bqkv[c0 * 6 + 4 + e], bv1 = bqkv[c1 * 6 + 4 + e];
        float te  = t[e * 32 + p];
        float sqq = (d == 0) ? (wq0 * wq0 * s00 + 2.f * wq0 * bq0 * m0 + N * bq0 * bq0)
                             : (wq1 * wq1 * s11 + 2.f * wq1 * bq1 * m1 + N * bq1 * bq1);
        float kk0 = wk0 * wk0 * s00 + 2.f * wk0 * bk0 * m0 + N * bk0 * bk0;
        float kk1 = wk1 * wk1 * s11 + 2.f * wk1 * bk1 * m1 + N * bk1 * bk1;
        float inq  = 1.f / fmaxf(sqrtf(fmaxf(sqq, 0.f)), 1e-12f);
        float ink0 = 1.f / fmaxf(sqrtf(fmaxf(kk0, 0.f)), 1e-12f);
        float ink1 = 1.f / fmaxf(sqrtf(fmaxf(kk1, 0.f)), 1e-12f);
        float qk0 = (d == 0) ? (wq0 * wk0 * s00 + wq0 * bk0 * m0 + bq0 * wk0 * m0 + N * bq0 * bk0)
                             : (wq1 * wk0 * s01 + wq1 * bk0 * m1 + bq1 * wk0 * m0 + N * bq1 * bk0);
        float qk1 = (d == 0) ? (wq0 * wk1 * s01 + wq0 * bk1 * m0 + bq0 * wk1 * m1 + N * bq0 * bk1)
                             : (wq1 * wk1 * s11 + wq1 * bk1 * m1 + bq1 * wk1 * m1 + N * bq1 * bk1);
        float L0 = qk0 * inq * ink0 * te, L1 = qk1 * inq * ink1 * te;
        float mx = fmaxf(L0, L1);
        float e0 = expf(L0 - mx), e1 = expf(L1 - mx);
        float iv = 1.f / (e0 + e1);
        float p0 = e0 * iv, p1 = e1 * iv;
        float f = wf[c * 2 + e];
        Aa += f * p0 * wv0;
        Bb += f * p1 * wv1;
        Cc += f * (p0 * bv0 + p1 * bv1);
    }
    A = Aa; B = Bb; C = Cc + bf[c];
}

// ---------------------------------------------------------------------------
// k_mega: 1x1 conv (in registers, patch-wise) + dw 2x2/s2 + idx permute +
// channel attention (collapsed linear map) + nidx permute + spatial attention
// (rank-2 Fourier/Bessel moments, O(N+M)) + group fuse + un1 + pixel shuffle.
// Grid: 32 = (b:2, jp:16). Block owns y3 channels 4jp..4jp+3 (needs only y1
// channels jp, jp+16) and BOTH spatial heads j=jp and j=jp+16.
// ---------------------------------------------------------------------------
__global__ __launch_bounds__(256) void k_mega(const float* __restrict__ x,
        const float* __restrict__ w1x1, const float* __restrict__ b1x1,
        const float* __restrict__ wdw,  const float* __restrict__ bdw,
        const float* __restrict__ ca_wqkv, const float* __restrict__ ca_bqkv,
        const float* __restrict__ ca_t,    const float* __restrict__ ca_wf,
        const float* __restrict__ ca_bf,
        const float* __restrict__ wqkv, const float* __restrict__ bqkv,
        const float* __restrict__ t,    const float* __restrict__ wf,
        const float* __restrict__ bfuse, const float* __restrict__ w1,
        const float* __restrict__ b1,   float* __restrict__ y8) {
    __shared__ float4 ly[1024];        // y3 pixel -> (ch 4jp+0..3)
    __shared__ float redg[10][4];
    __shared__ float momf[2][2][40];   // [h][e][39]
    int tid = threadIdx.x;
    int jp = blockIdx.x & 15;
    int b  = blockIdx.x >> 4;

    // ---- uniform params for the front ----
    const float2* x2 = (const float2*)(x + (size_t)b * 64 * 4096);
    const float* wr0 = w1x1 + jp * 64;
    const float* wr1 = w1x1 + (jp + 16) * 64;
    float bs0 = b1x1[jp], bs1 = b1x1[jp + 16];
    float4 wd0 = ((const float4*)wdw)[2 * jp];
    float4 wd1 = ((const float4*)wdw)[2 * jp + 32];
    float4 wd2 = ((const float4*)wdw)[2 * jp + 1];
    float4 wd3 = ((const float4*)wdw)[2 * jp + 33];
    float bd0 = bdw[2 * jp],     bd1 = bdw[2 * jp + 32];
    float bd2 = bdw[2 * jp + 1], bd3 = bdw[2 * jp + 33];

    // ---- phase A+B: conv in registers -> dw -> ly + Gram stats ----
    float sA00 = 0, sA01 = 0, sA11 = 0, mA0 = 0, mA1 = 0;
    float sB00 = 0, sB01 = 0, sB11 = 0, mB0 = 0, mB1 = 0;
#pragma unroll
    for (int s = 0; s < 4; ++s) {
        int p = s * 256 + tid;            // y3 pixel index (i=p>>5, j=p&31)
        int top = (p >> 5) * 64 + (p & 31);   // float2 index of row 2i, cols 2j..2j+1
        float t00 = 0, t01 = 0, t10 = 0, t11 = 0;   // y1[jp] 2x2 patch
        float u00 = 0, u01 = 0, u10 = 0, u11 = 0;   // y1[jp+16]
#pragma unroll 8
        for (int c = 0; c < 64; ++c) {
            float2 xt = x2[c * 2048 + top];
            float2 xb = x2[c * 2048 + top + 32];
            float wa = wr0[c], wb = wr1[c];
            t00 = fmaf(wa, xt.x, t00); t01 = fmaf(wa, xt.y, t01);
            t10 = fmaf(wa, xb.x, t10); t11 = fmaf(wa, xb.y, t11);
            u00 = fmaf(wb, xt.x, u00); u01 = fmaf(wb, xt.y, u01);
            u10 = fmaf(wb, xb.x, u10); u11 = fmaf(wb, xb.y, u11);
        }
        t00 += bs0; t01 += bs0; t10 += bs0; t11 += bs0;
        u00 += bs1; u01 += bs1; u10 += bs1; u11 += bs1;
        // dw + idx permute: y3 ch 4jp+{0,1,2,3} <- oc {2jp, 2jp+32, 2jp+1, 2jp+33}
        float a0 = fmaf(wd0.x, t00, fmaf(wd0.y, t01, fmaf(wd0.z, t10, fmaf(wd0.w, t11, bd0))));
        float a1 = fmaf(wd1.x, u00, fmaf(wd1.y, u01, fmaf(wd1.z, u10, fmaf(wd1.w, u11, bd1))));
        float a2 = fmaf(wd2.x, t00, fmaf(wd2.y, t01, fmaf(wd2.z, t10, fmaf(wd2.w, t11, bd2))));
        float a3 = fmaf(wd3.x, u00, fmaf(wd3.y, u01, fmaf(wd3.z, u10, fmaf(wd3.w, u11, bd3))));
        ly[p] = make_float4(a0, a1, a2, a3);
        sA00 = fmaf(a0, a0, sA00); sA01 = fmaf(a0, a1, sA01); sA11 = fmaf(a1, a1, sA11);
        mA0 += a0; mA1 += a1;
        sB00 = fmaf(a2, a2, sB00); sB01 = fmaf(a2, a3, sB01); sB11 = fmaf(a3, a3, sB11);
        mB0 += a2; mB1 += a3;
    }
#pragma unroll
    for (int off = 1; off < 64; off <<= 1) {
        sA00 += __shfl_xor(sA00, off, 64); sA01 += __shfl_xor(sA01, off, 64);
        sA11 += __shfl_xor(sA11, off, 64); mA0 += __shfl_xor(mA0, off, 64);
        mA1  += __shfl_xor(mA1,  off, 64);
        sB00 += __shfl_xor(sB00, off, 64); sB01 += __shfl_xor(sB01, off, 64);
        sB11 += __shfl_xor(sB11, off, 64); mB0 += __shfl_xor(mB0, off, 64);
        mB1  += __shfl_xor(mB1,  off, 64);
    }
    int wv = tid >> 6;
    if ((tid & 63) == 0) {
        redg[0][wv] = sA00; redg[1][wv] = sA01; redg[2][wv] = sA11;
        redg[3][wv] = mA0;  redg[4][wv] = mA1;
        redg[5][wv] = sB00; redg[6][wv] = sB01; redg[7][wv] = sB11;
        redg[8][wv] = mB0;  redg[9][wv] = mB1;
    }
    __syncthreads();
    sA00 = redg[0][0] + redg[0][1] + redg[0][2] + redg[0][3];
    sA01 = redg[1][0] + redg[1][1] + redg[1][2] + redg[1][3];
    sA11 = redg[2][0] + redg[2][1] + redg[2][2] + redg[2][3];
    mA0  = redg[3][0] + redg[3][1] + redg[3][2] + redg[3][3];
    mA1  = redg[4][0] + redg[4][1] + redg[4][2] + redg[4][3];
    sB00 = redg[5][0] + redg[5][1] + redg[5][2] + redg[5][3];
    sB01 = redg[6][0] + redg[6][1] + redg[6][2] + redg[6][3];
    sB11 = redg[7][0] + redg[7][1] + redg[7][2] + redg[7][3];
    mB0  = redg[8][0] + redg[8][1] + redg[8][2] + redg[8][3];
    mB1  = redg[9][0] + redg[9][1] + redg[9][2] + redg[9][3];

    // ---- phase C: ca coeffs for both heads (h == d) and both pairs ----
    float Aa[2], Ba[2], Ca[2], Ab[2], Bb[2], Cb[2];
#pragma unroll
    for (int h = 0; h < 2; ++h) {
        ca_coeffs(2 * jp,     h, sA00, sA01, sA11, mA0, mA1,
                  ca_wqkv, ca_bqkv, ca_t, ca_wf, ca_bf, Aa[h], Ba[h], Ca[h]);
        ca_coeffs(2 * jp + 1, h, sB00, sB01, sB11, mB0, mB1,
                  ca_wqkv, ca_bqkv, ca_t, ca_wf, ca_bf, Ab[h], Bb[h], Cb[h]);
    }

    // ---- phase D: key moments; wave w = (h, e), 16 keys/lane ----
    {
        int lane = tid & 63;
        int h = wv >> 1, e = wv & 1;
        int j = jp + 16 * h;
        int c0s = 2 * j, c1s = 2 * j + 1;
        float wk0 = wqkv[c0s * 6 + 2 + e], wk1 = wqkv[c1s * 6 + 2 + e];
        float bk0 = bqkv[c0s * 6 + 2 + e], bk1 = bqkv[c1s * 6 + 2 + e];
        float wv0 = wqkv[c0s * 6 + 4 + e], wv1 = wqkv[c1s * 6 + 4 + e];
        float bv0 = bqkv[c0s * 6 + 4 + e], bv1 = bqkv[c1s * 6 + 4 + e];
        float cAa = Aa[h], cBa = Ba[h], cCa = Ca[h];
        float cAb = Ab[h], cBb = Bb[h], cCb = Cb[h];
        float mom[39];
#pragma unroll
        for (int i = 0; i < 39; ++i) mom[i] = 0.f;
#pragma unroll
        for (int kk = 0; kk < 16; ++kk) {
            int m = lane + (kk << 6);
            float4 L = ly[m];
            float xa = fmaf(cAa, L.x, fmaf(cBa, L.y, cCa));
            float xb = fmaf(cAb, L.z, fmaf(cBb, L.w, cCb));
            float k0 = fmaf(wk0, xa, bk0), k1 = fmaf(wk1, xb, bk1);
            float inv = 1.f / fmaxf(sqrtf(k0 * k0 + k1 * k1), 1e-12f);
            float cp = k0 * inv, sp = k1 * inv;
            float v0 = fmaf(wv0, xa, bv0), v1 = fmaf(wv1, xb, bv1);
            mom[0] += 1.f; mom[1] += v0; mom[2] += v1;
            float c_m1 = 1.f, s_m1 = 0.f, c_r = cp, s_r = sp;
            float twoc = 2.f * cp;
#pragma unroll
            for (int r = 1; r <= NR; ++r) {
                int base = 3 + (r - 1) * 6;
                mom[base + 0] += c_r;
                mom[base + 1] = fmaf(c_r, v0, mom[base + 1]);
                mom[base + 2] = fmaf(c_r, v1, mom[base + 2]);
                mom[base + 3] += s_r;
                mom[base + 4] = fmaf(s_r, v0, mom[base + 4]);
                mom[base + 5] = fmaf(s_r, v1, mom[base + 5]);
                float cn = fmaf(twoc, c_r, -c_m1);
                float sn = fmaf(twoc, s_r, -s_m1);
                c_m1 = c_r; s_m1 = s_r; c_r = cn; s_r = sn;
            }
        }
#pragma unroll
        for (int i = 0; i < 39; ++i) {
            float v = mom[i];
            v += __shfl_xor(v, 1, 64);  v += __shfl_xor(v, 2, 64);
            v += __shfl_xor(v, 4, 64);  v += __shfl_xor(v, 8, 64);
            v += __shfl_xor(v, 16, 64); v += __shfl_xor(v, 32, 64);
            mom[i] = v;
        }
        float J[NR + 1];
        bessel_J(t[e * 32 + j], J);
        if (lane == 0) {
#pragma unroll
            for (int i = 0; i < 39; ++i) {
                int r = (i < 3) ? 0 : ((i - 3) / 6 + 1);
                momf[h][e][i] = mom[i] * J[r];
            }
        }
    }
    __syncthreads();

    // ---- phase E: queries (4 px/thread, both heads) + epilogue ----
#pragma unroll
    for (int s = 0; s < 4; ++s) {
        int n = s * 256 + tid;
        float4 L = ly[n];
#pragma unroll
        for (int h = 0; h < 2; ++h) {
            int j = jp + 16 * h;
            int c0s = 2 * j, c1s = 2 * j + 1;
            float xa = fmaf(Aa[h], L.x, fmaf(Ba[h], L.y, Ca[h]));
            float xb = fmaf(Ab[h], L.z, fmaf(Bb[h], L.w, Cb[h]));
            float oo[2][2];
#pragma unroll
            for (int e = 0; e < 2; ++e) {
                float wq0 = wqkv[c0s * 6 + e], wq1 = wqkv[c1s * 6 + e];
                float bq0 = bqkv[c0s * 6 + e], bq1 = bqkv[c1s * 6 + e];
                float q0 = fmaf(wq0, xa, bq0), q1 = fmaf(wq1, xb, bq1);
                float qi = 1.f / fmaxf(sqrtf(q0 * q0 + q1 * q1), 1e-12f);
                float a = q0 * qi, bq = q1 * qi;
                const float* M = momf[h][e];
                float den = M[0], o0 = M[1], o1 = M[2];
                float c_m1 = 1.f, s_m1 = 0.f, c_r = a, s_r = bq;
                float twoc = 2.f * a;
#pragma unroll
                for (int r = 1; r <= NR; ++r) {
                    int base = 3 + (r - 1) * 6;
                    den = fmaf(c_r, M[base + 0], den);
                    o0  = fmaf(c_r, M[base + 1], o0);
                    o1  = fmaf(c_r, M[base + 2], o1);
                    den = fmaf(s_r, M[base + 3], den);
                    o0  = fmaf(s_r, M[base + 4], o0);
                    o1  = fmaf(s_r, M[base + 5], o1);
                    float cn = fmaf(twoc, c_r, -c_m1);
                    float sn = fmaf(twoc, s_r, -s_m1);
                    c_m1 = c_r; s_m1 = s_r; c_r = cn; s_r = sn;
                }
                float rr = 1.f / den;
                oo[e][0] = o0 * rr;
                oo[e][1] = o1 * rr;
            }
            float t0 = fmaf(wf[c0s * 2], oo[0][0], fmaf(wf[c0s * 2 + 1], oo[1][0], bfuse[c0s]));
            float t1 = fmaf(wf[c1s * 2], oo[0][1], fmaf(wf[c1s * 2 + 1], oo[1][1], bfuse[c1s]));
            int i32 = n >> 5, j32 = n & 31;
            float* dst = y8 + (b * 32 + j) * 4096 + i32 * 128 + j32 * 2;
            float z0 = fmaf(w1[(4 * j + 0) * 2], t0, fmaf(w1[(4 * j + 0) * 2 + 1], t1, b1[4 * j + 0]));
            float z1 = fmaf(w1[(4 * j + 1) * 2], t0, fmaf(w1[(4 * j + 1) * 2 + 1], t1, b1[4 * j + 1]));
            float z2 = fmaf(w1[(4 * j + 2) * 2], t0, fmaf(w1[(4 * j + 2) * 2 + 1], t1, b1[4 * j + 2]));
            float z3 = fmaf(w1[(4 * j + 3) * 2], t0, fmaf(w1[(4 * j + 3) * 2 + 1], t1, b1[4 * j + 3]));
            *(float2*)(dst)      = make_float2(z0, z1);
            *(float2*)(dst + 64) = make_float2(z2, z3);
        }
    }
}

// ---------------------------------------------------------------------------
// kC: out[b,o,p] = sum_g w_un2[o,g]*y8[b,g,p] + b_un2[o];  (2,64,4096)
// ---------------------------------------------------------------------------
__global__ __launch_bounds__(256) void k_conv_un2(const float* __restrict__ y8,
        const float* __restrict__ w, const float* __restrict__ bias,
        float* __restrict__ out) {
    __shared__ float lx[32 * 64];
    __shared__ float lw[64 * 32];
    int tid = threadIdx.x;
    int gp0 = blockIdx.x * 64;
    int b = gp0 >> 12;
    int p0 = gp0 & 4095;
    for (int idx = tid; idx < 32 * 64; idx += 256) {
        int g = idx >> 6, pp = idx & 63;
        lx[idx] = y8[(b * 32 + g) * 4096 + p0 + pp];
    }
    for (int idx = tid; idx < 64 * 32; idx += 256) lw[idx] = w[idx];
    __syncthreads();
    int px = tid & 63, og = tid >> 6;
    float acc[16];
#pragma unroll
    for (int k = 0; k < 16; ++k) acc[k] = 0.f;
    for (int g = 0; g < 32; ++g) {
        float xv = lx[g * 64 + px];
#pragma unroll
        for (int k = 0; k < 16; ++k)
            acc[k] = fmaf(lw[(og * 16 + k) * 32 + g], xv, acc[k]);
    }
#pragma unroll
    for (int k = 0; k < 16; ++k) {
        int o = og * 16 + k;
        out[(b * 64 + o) * 4096 + p0 + px] = acc[k] + bias[o];
    }
}

extern "C" void kernel_launch(void* const* d_in, const int* in_sizes, int n_in,
                              void* d_out, int out_size, void* d_ws, size_t ws_size,
                              hipStream_t stream) {
    (void)in_sizes; (void)n_in; (void)out_size; (void)ws_size;
    const float* x       = (const float*)d_in[0];
    const float* w_sq1   = (const float*)d_in[1];
    const float* b_sq1   = (const float*)d_in[2];
    const float* w_sq2   = (const float*)d_in[3];
    const float* b_sq2   = (const float*)d_in[4];
    const float* ca_wqkv = (const float*)d_in[5];
    const float* ca_bqkv = (const float*)d_in[6];
    const float* ca_t    = (const float*)d_in[7];
    const float* ca_wf   = (const float*)d_in[8];
    const float* ca_bf   = (const float*)d_in[9];
    const float* sa_wqkv = (const float*)d_in[10];
    const float* sa_bqkv = (const float*)d_in[11];
    const float* sa_t    = (const float*)d_in[12];
    const float* sa_wf   = (const float*)d_in[13];
    const float* sa_bf   = (const float*)d_in[14];
    const float* w_un1   = (const float*)d_in[15];
    const float* b_un1   = (const float*)d_in[16];
    const float* w_un2   = (const float*)d_in[17];
    const float* b_un2   = (const float*)d_in[18];
    float* out = (float*)d_out;
    float* ws  = (float*)d_ws;
    float* y8 = ws;                 // (2,32,64,64) = 262144 floats

    k_mega<<<32, 256, 0, stream>>>(x, w_sq1, b_sq1, w_sq2, b_sq2,
                                   ca_wqkv, ca_bqkv, ca_t, ca_wf, ca_bf,
                                   sa_wqkv, sa_bqkv, sa_t, sa_wf, sa_bf,
                                   w_un1, b_un1, y8);
    k_conv_un2<<<128, 256, 0, stream>>>(y8, w_un2, b_un2, out);
}

// Round 5
// 109.795 us; speedup vs baseline: 1.2239x; 1.2239x over previous
//
#include <hip/hip_runtime.h>
#include <math.h>

#define NR 6   // Fourier terms r=1..NR; trunc error ~I_{NR+1}(1)/I_0(1) ~ 1.3e-6

typedef float v2f __attribute__((ext_vector_type(2)));

__device__ __forceinline__ v2f vfma2(v2f a, v2f b, v2f c) {
#if defined(__has_builtin)
#if __has_builtin(__builtin_elementwise_fma)
    return __builtin_elementwise_fma(a, b, c);
#else
    v2f r; r.x = fmaf(a.x, b.x, c.x); r.y = fmaf(a.y, b.y, c.y); return r;
#endif
#else
    v2f r; r.x = fmaf(a.x, b.x, c.x); r.y = fmaf(a.y, b.y, c.y); return r;
#endif
}

// J[r] = (r==0 ? 1 : 2) * I_r(t), modified Bessel, series (divisors fold to
// compile-time reciprocal multiplies after full unroll).
__device__ __forceinline__ void bessel_J(float t, float* J) {
    float h = 0.5f * t, q = h * h;
    float hp = 1.f, rf = 1.f;
#pragma unroll
    for (int r = 0; r <= NR; ++r) {
        if (r > 0) { hp *= h; rf *= (1.f / r); }
        float term = hp * rf, sum = term;
#pragma unroll
        for (int k = 1; k <= 12; ++k) {
            term *= q * (1.f / (k * (r + k)));
            sum += term;
        }
        J[r] = (r ? 2.f : 1.f) * sum;
    }
}

// ---------------------------------------------------------------------------
// kA: fused 1x1 conv (64->32) + depthwise 2x2/s2 conv + channel permute.
// Grid: 256 = (b:2, i32:32, q:4).  [proven R3 kernel, unchanged]
// ---------------------------------------------------------------------------
__global__ __launch_bounds__(256) void k_front(const float* __restrict__ x,
        const float* __restrict__ w1x1, const float* __restrict__ b1x1,
        const float* __restrict__ wdw,  const float* __restrict__ bdw,
        float* __restrict__ y3) {
    __shared__ float lxs[64 * 128];   // [c][col2]
    __shared__ float lwt[8][64];      // [gidx][c]
    int tid = threadIdx.x;
    int q   = blockIdx.x & 3;
    int i32 = (blockIdx.x >> 2) & 31;
    int b   = blockIdx.x >> 7;

    const float4* x4 = (const float4*)x;
#pragma unroll
    for (int i = 0; i < 8; ++i) {
        int f4 = tid + i * 256;
        int c  = f4 >> 5, cw = f4 & 31;
        ((float4*)lxs)[f4] = x4[(b * 64 + c) * 1024 + i32 * 32 + cw];
    }
    for (int idx = tid; idx < 512; idx += 256) {
        int gi = idx >> 6, c = idx & 63;
        int g = 4 * q + (gi & 3) + ((gi & 4) << 2);
        lwt[gi][c] = w1x1[g * 64 + c];
    }
    __syncthreads();

    int gidx = tid >> 5, col = tid & 31;
    int g = 4 * q + (gidx & 3) + ((gidx & 4) << 2);
    v2f acc0 = {0.f, 0.f}, acc1 = {0.f, 0.f};
    const v2f* lx2 = (const v2f*)lxs;
#pragma unroll 4
    for (int c = 0; c < 64; ++c) {
        float wv = lwt[gidx][c];
        v2f w2 = {wv, wv};
        acc0 = vfma2(w2, lx2[c * 64 + col], acc0);
        acc1 = vfma2(w2, lx2[c * 64 + 32 + col], acc1);
    }
    float bs = b1x1[g];
    float a00 = acc0.x + bs, a01 = acc0.y + bs;
    float a10 = acc1.x + bs, a11 = acc1.y + bs;
#pragma unroll
    for (int s = 0; s < 2; ++s) {
        int oc = 2 * g + s;
        int k  = 2 * (oc & 31) + (oc >> 5);   // permuted y3 channel
        float4 wd = ((const float4*)wdw)[oc];
        float v = bdw[oc];
        v = fmaf(wd.x, a00, v); v = fmaf(wd.y, a01, v);
        v = fmaf(wd.z, a10, v); v = fmaf(wd.w, a11, v);
        y3[(b * 64 + k) * 1024 + i32 * 32 + col] = v;
    }
}

// ---------------------------------------------------------------------------
// Channel-attention collapsed map (exact): y4[2p+d] = A*y3[2p]+B*y3[2p+1]+C.
// ---------------------------------------------------------------------------
__device__ __forceinline__ void ca_coeffs(int p, int d,
        float s00, float s01, float s11, float m0, float m1,
        const float* __restrict__ wqkv, const float* __restrict__ bqkv,
        const float* __restrict__ t,    const float* __restrict__ wf,
        const float* __restrict__ bf,   float& A, float& B, float& C) {
    const float N = 1024.f;
    int c0 = 2 * p, c1 = 2 * p + 1;
    int c  = 2 * p + d;
    float Aa = 0.f, Bb = 0.f, Cc = 0.f;
#pragma unroll
    for (int e = 0; e < 2; ++e) {
        float wq0 = wqkv[c0 * 6 + e],     wq1 = wqkv[c1 * 6 + e];
        float bq0 = bqkv[c0 * 6 + e],     bq1 = bqkv[c1 * 6 + e];
        float wk0 = wqkv[c0 * 6 + 2 + e], wk1 = wqkv[c1 * 6 + 2 + e];
        float bk0 = bqkv[c0 * 6 + 2 + e], bk1 = bqkv[c1 * 6 + 2 + e];
        float wv0 = wqkv[c0 * 6 + 4 + e], wv1 = wqkv[c1 * 6 + 4 + e];
        float bv0 = bqkv[c0 * 6 + 4 + e], bv1 = bqkv[c1 * 6 + 4 + e];
        float te  = t[e * 32 + p];
        float sqq = (d == 0) ? (wq0 * wq0 * s00 + 2.f * wq0 * bq0 * m0 + N * bq0 * bq0)
                             : (wq1 * wq1 * s11 + 2.f * wq1 * bq1 * m1 + N * bq1 * bq1);
        float kk0 = wk0 * wk0 * s00 + 2.f * wk0 * bk0 * m0 + N * bk0 * bk0;
        float kk1 = wk1 * wk1 * s11 + 2.f * wk1 * bk1 * m1 + N * bk1 * bk1;
        float inq  = 1.f / fmaxf(sqrtf(fmaxf(sqq, 0.f)), 1e-12f);
        float ink0 = 1.f / fmaxf(sqrtf(fmaxf(kk0, 0.f)), 1e-12f);
        float ink1 = 1.f / fmaxf(sqrtf(fmaxf(kk1, 0.f)), 1e-12f);
        float qk0 = (d == 0) ? (wq0 * wk0 * s00 + wq0 * bk0 * m0 + bq0 * wk0 * m0 + N * bq0 * bk0)
                             : (wq1 * wk0 * s01 + wq1 * bk0 * m1 + bq1 * wk0 * m0 + N * bq1 * bk0);
        float qk1 = (d == 0) ? (wq0 * wk1 * s01 + wq0 * bk1 * m0 + bq0 * wk1 * m1 + N * bq0 * bk1)
                             : (wq1 * wk1 * s11 + wq1 * bk1 * m1 + bq1 * wk1 * m1 + N * bq1 * bk1);
        float L0 = qk0 * inq * ink0 * te, L1 = qk1 * inq * ink1 * te;
        float mx = fmaxf(L0, L1);
        float e0 = expf(L0 - mx), e1 = expf(L1 - mx);
        float iv = 1.f / (e0 + e1);
        float p0 = e0 * iv, p1 = e1 * iv;
        float f = wf[c * 2 + e];
        Aa += f * p0 * wv0;
        Bb += f * p1 * wv1;
        Cc += f * (p0 * bv0 + p1 * bv1);
    }
    A = Aa; B = Bb; C = Cc + bf[c];
}

// ---------------------------------------------------------------------------
// kB: channel attention (collapsed) + nidx permute + spatial attention via
// rank-2 Fourier/Bessel moments (O(N+M)) + group fuse + un1 + pixel shuffle.
// Grid: 256 = (b:2, j:32, chunk:4); 256 threads.  [R3 kernel, NR 8->6]
// ---------------------------------------------------------------------------
__global__ __launch_bounds__(256) void k_attn(const float* __restrict__ y3,
        const float* __restrict__ ca_wqkv, const float* __restrict__ ca_bqkv,
        const float* __restrict__ ca_t,    const float* __restrict__ ca_wf,
        const float* __restrict__ ca_bf,
        const float* __restrict__ wqkv, const float* __restrict__ bqkv,
        const float* __restrict__ t,    const float* __restrict__ wf,
        const float* __restrict__ bfuse, const float* __restrict__ w1,
        const float* __restrict__ b1,   float* __restrict__ y8) {
    __shared__ float ly[4][1024];
    __shared__ float redg[10][4];
    __shared__ float redm[4][39];
    __shared__ float momf[2][39];
    int tid = threadIdx.x;
    int chunk = blockIdx.x & 3;
    int j = (blockIdx.x >> 2) & 31;
    int b = blockIdx.x >> 7;
    int jp = j & 15;
    int dsel = j >> 4;
    int c0 = 2 * j, c1 = 2 * j + 1;

    // ---- phase 1: stage 4 y3 channels + Gram stats for both ca pairs ----
    const float* base = y3 + (b * 64 + 4 * jp) * 1024;
    float sA00 = 0, sA01 = 0, sA11 = 0, mA0 = 0, mA1 = 0;
    float sB00 = 0, sB01 = 0, sB11 = 0, mB0 = 0, mB1 = 0;
#pragma unroll
    for (int r = 0; r < 4; ++r) {
        int n = tid + r * 256;
        float a0 = base[n], a1 = base[1024 + n];
        float a2 = base[2048 + n], a3 = base[3072 + n];
        ly[0][n] = a0; ly[1][n] = a1; ly[2][n] = a2; ly[3][n] = a3;
        sA00 = fmaf(a0, a0, sA00); sA01 = fmaf(a0, a1, sA01); sA11 = fmaf(a1, a1, sA11);
        mA0 += a0; mA1 += a1;
        sB00 = fmaf(a2, a2, sB00); sB01 = fmaf(a2, a3, sB01); sB11 = fmaf(a3, a3, sB11);
        mB0 += a2; mB1 += a3;
    }
#pragma unroll
    for (int off = 1; off < 64; off <<= 1) {
        sA00 += __shfl_xor(sA00, off, 64); sA01 += __shfl_xor(sA01, off, 64);
        sA11 += __shfl_xor(sA11, off, 64); mA0 += __shfl_xor(mA0, off, 64);
        mA1  += __shfl_xor(mA1,  off, 64);
        sB00 += __shfl_xor(sB00, off, 64); sB01 += __shfl_xor(sB01, off, 64);
        sB11 += __shfl_xor(sB11, off, 64); mB0 += __shfl_xor(mB0, off, 64);
        mB1  += __shfl_xor(mB1,  off, 64);
    }
    int wid = tid >> 6;
    if ((tid & 63) == 0) {
        redg[0][wid] = sA00; redg[1][wid] = sA01; redg[2][wid] = sA11;
        redg[3][wid] = mA0;  redg[4][wid] = mA1;
        redg[5][wid] = sB00; redg[6][wid] = sB01; redg[7][wid] = sB11;
        redg[8][wid] = mB0;  redg[9][wid] = mB1;
    }
    __syncthreads();
    sA00 = redg[0][0] + redg[0][1] + redg[0][2] + redg[0][3];
    sA01 = redg[1][0] + redg[1][1] + redg[1][2] + redg[1][3];
    sA11 = redg[2][0] + redg[2][1] + redg[2][2] + redg[2][3];
    mA0  = redg[3][0] + redg[3][1] + redg[3][2] + redg[3][3];
    mA1  = redg[4][0] + redg[4][1] + redg[4][2] + redg[4][3];
    sB00 = redg[5][0] + redg[5][1] + redg[5][2] + redg[5][3];
    sB01 = redg[6][0] + redg[6][1] + redg[6][2] + redg[6][3];
    sB11 = redg[7][0] + redg[7][1] + redg[7][2] + redg[7][3];
    mB0  = redg[8][0] + redg[8][1] + redg[8][2] + redg[8][3];
    mB1  = redg[9][0] + redg[9][1] + redg[9][2] + redg[9][3];

    float Aa, Ba, Ca, Ab, Bb, Cb;
    ca_coeffs(2 * jp,     dsel, sA00, sA01, sA11, mA0, mA1,
              ca_wqkv, ca_bqkv, ca_t, ca_wf, ca_bf, Aa, Ba, Ca);
    ca_coeffs(2 * jp + 1, dsel, sB00, sB01, sB11, mB0, mB1,
              ca_wqkv, ca_bqkv, ca_t, ca_wf, ca_bf, Ab, Bb, Cb);

    // ---- phase 2: key moments (thread-half e2, 8 keys each) ----
    int e2 = tid >> 7, l = tid & 127;
    float wk0 = wqkv[c0 * 6 + 2 + e2], wk1 = wqkv[c1 * 6 + 2 + e2];
    float bk0 = bqkv[c0 * 6 + 2 + e2], bk1 = bqkv[c1 * 6 + 2 + e2];
    float wv0 = wqkv[c0 * 6 + 4 + e2], wv1 = wqkv[c1 * 6 + 4 + e2];
    float bv0 = bqkv[c0 * 6 + 4 + e2], bv1 = bqkv[c1 * 6 + 4 + e2];
    float mom[39];
#pragma unroll
    for (int i = 0; i < 39; ++i) mom[i] = 0.f;
#pragma unroll
    for (int kk = 0; kk < 8; ++kk) {
        int m = l + (kk << 7);
        float xa = fmaf(Aa, ly[0][m], fmaf(Ba, ly[1][m], Ca));
        float xb = fmaf(Ab, ly[2][m], fmaf(Bb, ly[3][m], Cb));
        float k0 = fmaf(wk0, xa, bk0), k1 = fmaf(wk1, xb, bk1);
        float inv = 1.f / fmaxf(sqrtf(k0 * k0 + k1 * k1), 1e-12f);
        float cp = k0 * inv, sp = k1 * inv;
        float v0 = fmaf(wv0, xa, bv0), v1 = fmaf(wv1, xb, bv1);
        mom[0] += 1.f; mom[1] += v0; mom[2] += v1;
        float c_m1 = 1.f, s_m1 = 0.f, c_r = cp, s_r = sp;
        float twoc = 2.f * cp;
#pragma unroll
        for (int r = 1; r <= NR; ++r) {
            int bi = 3 + (r - 1) * 6;
            mom[bi + 0] += c_r;
            mom[bi + 1] = fmaf(c_r, v0, mom[bi + 1]);
            mom[bi + 2] = fmaf(c_r, v1, mom[bi + 2]);
            mom[bi + 3] += s_r;
            mom[bi + 4] = fmaf(s_r, v0, mom[bi + 4]);
            mom[bi + 5] = fmaf(s_r, v1, mom[bi + 5]);
            float cn = fmaf(twoc, c_r, -c_m1);
            float sn = fmaf(twoc, s_r, -s_m1);
            c_m1 = c_r; s_m1 = s_r; c_r = cn; s_r = sn;
        }
    }
#pragma unroll
    for (int i = 0; i < 39; ++i) {
        float v = mom[i];
        v += __shfl_xor(v, 1, 64);  v += __shfl_xor(v, 2, 64);
        v += __shfl_xor(v, 4, 64);  v += __shfl_xor(v, 8, 64);
        v += __shfl_xor(v, 16, 64); v += __shfl_xor(v, 32, 64);
        mom[i] = v;
    }
    if ((tid & 63) == 0) {
#pragma unroll
        for (int i = 0; i < 39; ++i) redm[wid][i] = mom[i];
    }
    __syncthreads();
    if (tid < 78) {
        int e = (tid >= 39) ? 1 : 0;
        int i = tid - 39 * e;
        int r = (i < 3) ? 0 : ((i - 3) / 6 + 1);
        float J[NR + 1];
        bessel_J(t[e * 32 + j], J);
        momf[e][i] = (redm[2 * e][i] + redm[2 * e + 1][i]) * J[r];
    }
    __syncthreads();

    // ---- phase 3: queries (1 per thread, both e) ----
    int n = (chunk << 8) + tid;
    float xan = fmaf(Aa, ly[0][n], fmaf(Ba, ly[1][n], Ca));
    float xbn = fmaf(Ab, ly[2][n], fmaf(Bb, ly[3][n], Cb));
    float oo[2][2];
#pragma unroll
    for (int e = 0; e < 2; ++e) {
        float wq0 = wqkv[c0 * 6 + e], wq1 = wqkv[c1 * 6 + e];
        float bq0 = bqkv[c0 * 6 + e], bq1 = bqkv[c1 * 6 + e];
        float q0 = fmaf(wq0, xan, bq0), q1 = fmaf(wq1, xbn, bq1);
        float qi = 1.f / fmaxf(sqrtf(q0 * q0 + q1 * q1), 1e-12f);
        float a = q0 * qi, bq = q1 * qi;
        const float* M = momf[e];
        float den = M[0], o0 = M[1], o1 = M[2];
        float c_m1 = 1.f, s_m1 = 0.f, c_r = a, s_r = bq;
        float twoc = 2.f * a;
#pragma unroll
        for (int r = 1; r <= NR; ++r) {
            int bi = 3 + (r - 1) * 6;
            den = fmaf(c_r, M[bi + 0], den);
            o0  = fmaf(c_r, M[bi + 1], o0);
            o1  = fmaf(c_r, M[bi + 2], o1);
            den = fmaf(s_r, M[bi + 3], den);
            o0  = fmaf(s_r, M[bi + 4], o0);
            o1  = fmaf(s_r, M[bi + 5], o1);
            float cn = fmaf(twoc, c_r, -c_m1);
            float sn = fmaf(twoc, s_r, -s_m1);
            c_m1 = c_r; s_m1 = s_r; c_r = cn; s_r = sn;
        }
        float rr = 1.f / den;
        oo[e][0] = o0 * rr;
        oo[e][1] = o1 * rr;
    }
    // ---- epilogue: group fuse + un1 + pixel shuffle ----
    float t0 = fmaf(wf[c0 * 2], oo[0][0], fmaf(wf[c0 * 2 + 1], oo[1][0], bfuse[c0]));
    float t1 = fmaf(wf[c1 * 2], oo[0][1], fmaf(wf[c1 * 2 + 1], oo[1][1], bfuse[c1]));
    int i32 = n >> 5, j32 = n & 31;
    float* dst = y8 + (b * 32 + j) * 4096 + (i32 * 2) * 64 + j32 * 2;
    float z0 = fmaf(w1[(4 * j + 0) * 2], t0, fmaf(w1[(4 * j + 0) * 2 + 1], t1, b1[4 * j + 0]));
    float z1 = fmaf(w1[(4 * j + 1) * 2], t0, fmaf(w1[(4 * j + 1) * 2 + 1], t1, b1[4 * j + 1]));
    float z2 = fmaf(w1[(4 * j + 2) * 2], t0, fmaf(w1[(4 * j + 2) * 2 + 1], t1, b1[4 * j + 2]));
    float z3 = fmaf(w1[(4 * j + 3) * 2], t0, fmaf(w1[(4 * j + 3) * 2 + 1], t1, b1[4 * j + 3]));
    *(float2*)(dst)      = make_float2(z0, z1);
    *(float2*)(dst + 64) = make_float2(z2, z3);
}

// ---------------------------------------------------------------------------
// kC: out[b,o,p] = sum_g w_un2[o,g]*y8[b,g,p] + b_un2[o];  (2,64,4096)
// ---------------------------------------------------------------------------
__global__ __launch_bounds__(256) void k_conv_un2(const float* __restrict__ y8,
        const float* __restrict__ w, const float* __restrict__ bias,
        float* __restrict__ out) {
    __shared__ float lx[32 * 64];
    __shared__ float lw[64 * 32];
    int tid = threadIdx.x;
    int gp0 = blockIdx.x * 64;
    int b = gp0 >> 12;
    int p0 = gp0 & 4095;
    for (int idx = tid; idx < 32 * 64; idx += 256) {
        int g = idx >> 6, pp = idx & 63;
        lx[idx] = y8[(b * 32 + g) * 4096 + p0 + pp];
    }
    for (int idx = tid; idx < 64 * 32; idx += 256) lw[idx] = w[idx];
    __syncthreads();
    int px = tid & 63, og = tid >> 6;
    float acc[16];
#pragma unroll
    for (int k = 0; k < 16; ++k) acc[k] = 0.f;
    for (int g = 0; g < 32; ++g) {
        float xv = lx[g * 64 + px];
#pragma unroll
        for (int k = 0; k < 16; ++k)
            acc[k] = fmaf(lw[(og * 16 + k) * 32 + g], xv, acc[k]);
    }
#pragma unroll
    for (int k = 0; k < 16; ++k) {
        int o = og * 16 + k;
        out[(b * 64 + o) * 4096 + p0 + px] = acc[k] + bias[o];
    }
}

extern "C" void kernel_launch(void* const* d_in, const int* in_sizes, int n_in,
                              void* d_out, int out_size, void* d_ws, size_t ws_size,
                              hipStream_t stream) {
    (void)in_sizes; (void)n_in; (void)out_size; (void)ws_size;
    const float* x       = (const float*)d_in[0];
    const float* w_sq1   = (const float*)d_in[1];
    const float* b_sq1   = (const float*)d_in[2];
    const float* w_sq2   = (const float*)d_in[3];
    const float* b_sq2   = (const float*)d_in[4];
    const float* ca_wqkv = (const float*)d_in[5];
    const float* ca_bqkv = (const float*)d_in[6];
    const float* ca_t    = (const float*)d_in[7];
    const float* ca_wf   = (const float*)d_in[8];
    const float* ca_bf   = (const float*)d_in[9];
    const float* sa_wqkv = (const float*)d_in[10];
    const float* sa_bqkv = (const float*)d_in[11];
    const float* sa_t    = (const float*)d_in[12];
    const float* sa_wf   = (const float*)d_in[13];
    const float* sa_bf   = (const float*)d_in[14];
    const float* w_un1   = (const float*)d_in[15];
    const float* b_un1   = (const float*)d_in[16];
    const float* w_un2   = (const float*)d_in[17];
    const float* b_un2   = (const float*)d_in[18];
    float* out = (float*)d_out;
    float* ws  = (float*)d_ws;
    float* y3 = ws;                 // (2,64,1024)  = 131072 floats
    float* y8 = ws + 131072;        // (2,32,64,64) = 262144 floats

    k_front<<<256, 256, 0, stream>>>(x, w_sq1, b_sq1, w_sq2, b_sq2, y3);
    k_attn <<<256, 256, 0, stream>>>(y3, ca_wqkv, ca_bqkv, ca_t, ca_wf, ca_bf,
                                     sa_wqkv, sa_bqkv, sa_t, sa_wf, sa_bf,
                                     w_un1, b_un1, y8);
    k_conv_un2<<<128, 256, 0, stream>>>(y8, w_un2, b_un2, out);
}